// Round 1
// baseline (20398.175 us; speedup 1.0000x reference)
//
#include <hip/hip_runtime.h>
#include <cstddef>

// ---------------------------------------------------------------------------
// Direct convolution, VALID padding, NCHW / OIHW, fp32, optional ReLU.
// Block: 256 threads -> output tile 64(x) x 32(y) x 4(oc).
// Thread micro-tile: 8 consecutive x positions x 4 output channels.
// Per-ic staging of input patch + weight slice into LDS.
// ---------------------------------------------------------------------------

template <int K>
__global__ __launch_bounds__(256) void conv_kernel(
    const float* __restrict__ in, const float* __restrict__ wgt,
    const float* __restrict__ bias, float* __restrict__ out,
    int IC, int OC, int H, int W, int Ho, int Wo, int relu)
{
    constexpr int TY = 32;
    constexpr int TX = 64;
    constexpr int ROWS = TY + K - 1;
    constexpr int STRIDE = (K == 1) ? 64 : 76;   // >= read extent, mult of 4
    constexpr int NREG = (K == 7) ? 4 : (K == 1 ? 2 : 3); // float4 row regs

    __shared__ float s_in[ROWS * STRIDE];
    __shared__ float s_w[K * K * 4];

    const int tid = threadIdx.x;
    const int g   = tid & 7;    // x-group: covers x = x0 + g*8 .. +7
    const int ty  = tid >> 3;   // y within tile, 0..31
    const int x0  = blockIdx.x * TX;
    const int y0  = blockIdx.y * TY;
    const int oc0 = blockIdx.z * 4;

    float acc[8][4];
#pragma unroll
    for (int r = 0; r < 8; ++r)
#pragma unroll
        for (int o = 0; o < 4; ++o) acc[r][o] = 0.0f;

    for (int ic = 0; ic < IC; ++ic) {
        // ---- stage input patch for this ic ----
        const float* ip = in + (size_t)ic * H * W;
        for (int idx = tid; idx < ROWS * STRIDE; idx += 256) {
            int rr = idx / STRIDE;
            int cc = idx - rr * STRIDE;
            int yy = y0 + rr;
            int xx = x0 + cc;
            float v = 0.0f;
            if (yy < H && xx < W) v = ip[(size_t)yy * W + xx];
            s_in[idx] = v;
        }
        // ---- stage weights: layout [ky*K+kx][oc4] ----
        if (tid < K * K * 4) {
            int o  = tid & 3;
            int kk = tid >> 2;
            float wv = 0.0f;
            int oc = oc0 + o;
            if (oc < OC) wv = wgt[((size_t)oc * IC + ic) * (K * K) + kk];
            s_w[tid] = wv;
        }
        __syncthreads();

        // ---- accumulate ----
#pragma unroll
        for (int ky = 0; ky < K; ++ky) {
            const float4* rp = (const float4*)&s_in[(ty + ky) * STRIDE + g * 8];
            float4 rv[NREG];
#pragma unroll
            for (int q = 0; q < NREG; ++q) rv[q] = rp[q];
            float row[NREG * 4];
#pragma unroll
            for (int q = 0; q < NREG; ++q) {
                row[4 * q + 0] = rv[q].x;
                row[4 * q + 1] = rv[q].y;
                row[4 * q + 2] = rv[q].z;
                row[4 * q + 3] = rv[q].w;
            }
            float4 wv[K];
#pragma unroll
            for (int kx = 0; kx < K; ++kx)
                wv[kx] = *(const float4*)&s_w[(ky * K + kx) * 4];
#pragma unroll
            for (int kx = 0; kx < K; ++kx) {
#pragma unroll
                for (int r = 0; r < 8; ++r) {
                    float iv = row[kx + r];
                    acc[r][0] = fmaf(iv, wv[kx].x, acc[r][0]);
                    acc[r][1] = fmaf(iv, wv[kx].y, acc[r][1]);
                    acc[r][2] = fmaf(iv, wv[kx].z, acc[r][2]);
                    acc[r][3] = fmaf(iv, wv[kx].w, acc[r][3]);
                }
            }
        }
        __syncthreads();
    }

    // ---- store ----
    const int y = y0 + ty;
    if (y < Ho) {
#pragma unroll
        for (int o = 0; o < 4; ++o) {
            int oc = oc0 + o;
            if (oc < OC) {
                float b = bias[oc];
                float* op = out + ((size_t)oc * Ho + y) * Wo;
#pragma unroll
                for (int r = 0; r < 8; ++r) {
                    int x = x0 + g * 8 + r;
                    if (x < Wo) {
                        float v = acc[r][o] + b;
                        if (relu) v = fmaxf(v, 0.0f);
                        op[x] = v;
                    }
                }
            }
        }
    }
}

// ---------------------------------------------------------------------------
// Bicubic warp: builds the 15-channel "warps" tensor for one batch image.
// disp: 256x256 (1 ch), cf: 22x256x256 colorFeatures slice, out: 15x256x256.
// Replicates the reference arithmetic order exactly.
// ---------------------------------------------------------------------------

__device__ inline void cubicw(float t, float w[4])
{
    const float A = -0.75f;
    float u;
    u = t + 1.0f; w[0] = ((A * u - 5.0f * A) * u + 8.0f * A) * u - 4.0f * A;
    u = t;        w[1] = ((A + 2.0f) * u - (A + 3.0f)) * u * u + 1.0f;
    u = 1.0f - t; w[2] = ((A + 2.0f) * u - (A + 3.0f)) * u * u + 1.0f;
    u = 2.0f - t; w[3] = ((A * u - 5.0f * A) * u + 8.0f * A) * u - 4.0f * A;
}

__global__ __launch_bounds__(256) void warp_kernel(
    const float* __restrict__ disp, const float* __restrict__ cf,
    float* __restrict__ out)
{
    const int P = 256 * 256;
    int idx = blockIdx.x * 256 + threadIdx.x;   // exactly 65536 threads
    int u = idx >> 8;     // row
    int v = idx & 255;    // col

    float d  = disp[idx];
    float q0 = cf[20 * P + idx];
    float q1 = cf[21 * P + idx];

    for (int i = 0; i < 4; ++i) {
        const float* img = cf + (size_t)(5 * i) * P;   // 3 color ch + 2 p ch
        float p0 = img[3 * P + idx];
        float p1 = img[4 * P + idx];
        // loc in (row, col); then reversed before grid_sample
        float lr = (float)u + (p0 - q0) * d;
        float lc = (float)v + (p1 - q1) * d;
        float gr = (lr / 255.0f - 0.5f) * 2.0f;
        float gc = (lc / 255.0f - 0.5f) * 2.0f;
        // after [..., ::-1]: grid[...,0] = gc -> x (col), grid[...,1] = gr -> y
        float x = ((gc + 1.0f) * 256.0f - 1.0f) * 0.5f;
        float y = ((gr + 1.0f) * 256.0f - 1.0f) * 0.5f;
        float xf = floorf(x), yf = floorf(y);
        float tx = x - xf, tyy = y - yf;
        float wx[4], wy[4];
        cubicw(tx, wx);
        cubicw(tyy, wy);
        int xi = (int)xf, yi = (int)yf;
        float a0 = 0.0f, a1 = 0.0f, a2 = 0.0f;
#pragma unroll
        for (int ii = 0; ii < 4; ++ii) {
            int yy = yi - 1 + ii;
            bool vy = (yy >= 0) && (yy < 256);
            int yc = min(max(yy, 0), 255);
#pragma unroll
            for (int jj = 0; jj < 4; ++jj) {
                int xx = xi - 1 + jj;
                bool vv = vy && (xx >= 0) && (xx < 256);
                int xc = min(max(xx, 0), 255);
                float w = vv ? wy[ii] * wx[jj] : 0.0f;
                int pos = yc * 256 + xc;
                a0 = fmaf(img[pos], w, a0);
                a1 = fmaf(img[P + pos], w, a1);
                a2 = fmaf(img[2 * P + pos], w, a2);
            }
        }
        out[(3 * i + 0) * P + idx] = a0;
        out[(3 * i + 1) * P + idx] = a1;
        out[(3 * i + 2) * P + idx] = a2;
    }
    out[12 * P + idx] = d;
    out[13 * P + idx] = q0;
    out[14 * P + idx] = q1;
}

// ---------------------------------------------------------------------------

static void launch_conv(int K, const float* in, const float* w, const float* b,
                        float* out, int IC, int OC, int H, int W, int relu,
                        hipStream_t s)
{
    int Ho = H - K + 1, Wo = W - K + 1;
    dim3 grid((Wo + 63) / 64, (Ho + 31) / 32, (OC + 3) / 4);
    dim3 blk(256);
    switch (K) {
    case 7: conv_kernel<7><<<grid, blk, 0, s>>>(in, w, b, out, IC, OC, H, W, Ho, Wo, relu); break;
    case 5: conv_kernel<5><<<grid, blk, 0, s>>>(in, w, b, out, IC, OC, H, W, Ho, Wo, relu); break;
    case 3: conv_kernel<3><<<grid, blk, 0, s>>>(in, w, b, out, IC, OC, H, W, Ho, Wo, relu); break;
    case 1: conv_kernel<1><<<grid, blk, 0, s>>>(in, w, b, out, IC, OC, H, W, Ho, Wo, relu); break;
    }
}

extern "C" void kernel_launch(void* const* d_in, const int* in_sizes, int n_in,
                              void* d_out, int out_size, void* d_ws, size_t ws_size,
                              hipStream_t stream)
{
    const float* dF  = (const float*)d_in[0];   // 4 x 200 x 268 x 268
    const float* cF  = (const float*)d_in[1];   // 4 x 22 x 256 x 256
    const float* dw1 = (const float*)d_in[2];
    const float* db1 = (const float*)d_in[3];
    const float* dw2 = (const float*)d_in[4];
    const float* db2 = (const float*)d_in[5];
    const float* dw3 = (const float*)d_in[6];
    const float* db3 = (const float*)d_in[7];
    const float* dw4 = (const float*)d_in[8];
    const float* db4 = (const float*)d_in[9];
    const float* cw1 = (const float*)d_in[10];
    const float* cb1 = (const float*)d_in[11];
    const float* cw2 = (const float*)d_in[12];
    const float* cb2 = (const float*)d_in[13];
    const float* cw3 = (const float*)d_in[14];
    const float* cb3 = (const float*)d_in[15];
    const float* cw4 = (const float*)d_in[16];
    const float* cb4 = (const float*)d_in[17];

    float* outp = (float*)d_out;

    // workspace layout (floats)
    float* bufA = (float*)d_ws;                 // up to 100*262*262 = 6,864,400
    float* bufB = bufA + 6864400;               // up to 100*258*258 = 6,656,400
    float* disp = bufB + 6656400;               // 65,536
    float* wrp  = disp + 65536;                 // 15*65,536 = 983,040
    // total ~58.3 MB

    for (int n = 0; n < 4; ++n) {
        const float* x0  = dF + (size_t)n * 200 * 268 * 268;
        const float* cfn = cF + (size_t)n * 22 * 256 * 256;
        float* outn = outp + (size_t)n * 3 * 244 * 244;

        // disparity net
        launch_conv(7, x0,   dw1, db1, bufA, 200, 100, 268, 268, 1, stream);
        launch_conv(5, bufA, dw2, db2, bufB, 100, 100, 262, 262, 1, stream);
        launch_conv(3, bufB, dw3, db3, bufA, 100,  50, 258, 258, 1, stream);
        launch_conv(1, bufA, dw4, db4, disp,  50,   1, 256, 256, 0, stream);

        // warp
        warp_kernel<<<dim3(256), dim3(256), 0, stream>>>(disp, cfn, wrp);

        // color net
        launch_conv(7, wrp,  cw1, cb1, bufA,  15, 100, 256, 256, 1, stream);
        launch_conv(5, bufA, cw2, cb2, bufB, 100, 100, 250, 250, 1, stream);
        launch_conv(3, bufB, cw3, cb3, bufA, 100,  50, 246, 246, 1, stream);
        launch_conv(1, bufA, cw4, cb4, outn,  50,   3, 244, 244, 0, stream);
    }
}

// Round 2
// 5087.516 us; speedup vs baseline: 4.0095x; 4.0095x over previous
//
#include <hip/hip_runtime.h>
#include <cstddef>
#include <cstdint>

typedef __attribute__((ext_vector_type(8))) short bf16x8;
typedef __attribute__((ext_vector_type(4))) float f32x4;

__device__ __forceinline__ unsigned short f2bf(float f) {
    unsigned u = __float_as_uint(f);
    u += 0x7fffu + ((u >> 16) & 1u);
    return (unsigned short)(u >> 16);
}
__device__ __forceinline__ float bf2f(unsigned short h) {
    return __uint_as_float(((unsigned)h) << 16);
}

// ---------------------------------------------------------------------------
// Weight transform: OIHW fp32 -> Bt[kstep][plane(hi,lo)][OCp][32slots] bf16.
// kstep = (chunk*K + ky)*R + run ; slot j: flat=run*32+j -> x_off=flat/24,
// ic = chunk*24 + flat%24. Zero-pads oc>=OC, ic>=IC, x_off>=K.
// ---------------------------------------------------------------------------
__global__ __launch_bounds__(256) void wtrans_kernel(
    const float* __restrict__ w, unsigned short* __restrict__ Bt,
    int IC, int OC, int OCp, int K, int R, int ksteps)
{
    int gid = blockIdx.x * 256 + threadIdx.x;
    if (gid >= ksteps * OCp) return;
    int ks = gid / OCp;
    int oc = gid - ks * OCp;
    int run = ks % R;
    int t2 = ks / R;
    int ky = t2 % K;
    int chunk = t2 / K;
    unsigned short* ph = Bt + ((size_t)(ks * 2 + 0) * OCp + oc) * 32;
    unsigned short* pl = ph + (size_t)OCp * 32;
    for (int j = 0; j < 32; ++j) {
        int flat = run * 32 + j;
        int xo = flat / 24;
        int icl = flat - xo * 24;
        int ic = chunk * 24 + icl;
        float v = 0.0f;
        if (oc < OC && ic < IC && xo < K)
            v = w[(((size_t)oc * IC + ic) * K + ky) * K + xo];
        unsigned short h = f2bf(v);
        unsigned short l = f2bf(v - bf2f(h));
        ph[j] = h;
        pl[j] = l;
    }
}

// ---------------------------------------------------------------------------
// Implicit-GEMM conv via MFMA 16x16x32 bf16, split-precision (3 MFMAs).
// A = activations (M=spatial), staged in LDS hi/lo per 24-ic chunk.
// B = transformed weights (N=oc), read straight from global (L1/L2).
// Block: 256 thr = 4 waves, each wave: 4 m-tiles (2 rows x 2 xhalves) x NW n-tiles.
// Tile: 8y x 32x spatial, OCp = NW*16 oc. Persistent grid over (img,y,x) tiles.
// Shift-origin tiles (no OOB stores; duplicate identical writes are benign).
// ---------------------------------------------------------------------------
template<int K, int NW, bool NCHW_IN, bool RELU>
__global__ __launch_bounds__(256, 2) void conv_mfma(
    const float* __restrict__ in, const unsigned short* __restrict__ Bt,
    const float* __restrict__ bias, float* __restrict__ out,
    int Hin, int Win, int IC, int OC, int Ho, int Wo,
    int nchunks, int xb, int yb, int nimg,
    long inStride, long outStride)
{
    constexpr int CB = 24;                       // ic per chunk
    constexpr int R  = (K * CB + 31) / 32;       // k-runs per ky
    constexpr int PH = 8 + K - 1;
    constexpr int PW = 32 + (R * 32 - 1) / CB + 1;
    constexpr int OCp = NW * 16;
    constexpr int PATCH = PH * PW * CB;

    __shared__ __align__(16) unsigned short s_hi[PATCH];
    __shared__ __align__(16) unsigned short s_lo[PATCH];

    const int tid   = threadIdx.x;
    const int lane  = tid & 63;
    const int wave  = tid >> 6;
    const int laneM = lane & 15;
    const int laneK = lane >> 4;
    const int laneA = laneM * CB + laneK * 8;

    const int tilesPerImg = xb * yb;
    const int totTiles = tilesPerImg * nimg;

    #pragma unroll 1
    for (int t = blockIdx.x; t < totTiles; t += gridDim.x) {
        int img = t / tilesPerImg;
        int rem = t - img * tilesPerImg;
        int byi = rem / xb;
        int bxi = rem - byi * xb;
        int y0 = byi * 8;  if (y0 > Ho - 8)  y0 = Ho - 8;
        int x0 = bxi * 32; if (x0 > Wo - 32) x0 = Wo - 32;

        const float* inI = in + (size_t)img * inStride;
        float* outI = out + (size_t)img * outStride;

        f32x4 acc[4][NW];
        #pragma unroll
        for (int m = 0; m < 4; ++m)
            #pragma unroll
            for (int n = 0; n < NW; ++n)
                acc[m][n] = (f32x4){0.f, 0.f, 0.f, 0.f};

        #pragma unroll 1
        for (int chunk = 0; chunk < nchunks; ++chunk) {
            // ----- stage input patch (hi/lo bf16) for this ic chunk -----
            if (NCHW_IN) {
                #pragma unroll 1
                for (int e = tid; e < PATCH; e += 256) {
                    int icl = e / (PH * PW);
                    int pix = e - icl * (PH * PW);
                    int py = pix / PW;
                    int px = pix - py * PW;
                    int gic = chunk * CB + icl;
                    int xg = x0 + px;
                    float v = 0.0f;
                    if (gic < IC && xg < Win)
                        v = inI[((size_t)gic * Hin + (y0 + py)) * Win + xg];
                    unsigned short h = f2bf(v);
                    int o = pix * CB + icl;
                    s_hi[o] = h;
                    s_lo[o] = f2bf(v - bf2f(h));
                }
            } else if ((IC & 3) == 0) {
                constexpr int NP4 = PH * PW * (CB / 4);
                #pragma unroll 1
                for (int e = tid; e < NP4; e += 256) {
                    int pix = e / 6;
                    int s   = e - pix * 6;
                    int py = pix / PW;
                    int px = pix - py * PW;
                    int gic = chunk * CB + s * 4;
                    int xg = x0 + px;
                    float4 v = {0.f, 0.f, 0.f, 0.f};
                    if (xg < Win) {
                        const float* p = inI + ((size_t)(y0 + py) * Win + xg) * IC + gic;
                        if (gic + 3 < IC) v = *(const float4*)p;
                        else {
                            if (gic + 0 < IC) v.x = p[0];
                            if (gic + 1 < IC) v.y = p[1];
                            if (gic + 2 < IC) v.z = p[2];
                            if (gic + 3 < IC) v.w = p[3];
                        }
                    }
                    int o = pix * CB + s * 4;
                    unsigned short h;
                    h = f2bf(v.x); s_hi[o + 0] = h; s_lo[o + 0] = f2bf(v.x - bf2f(h));
                    h = f2bf(v.y); s_hi[o + 1] = h; s_lo[o + 1] = f2bf(v.y - bf2f(h));
                    h = f2bf(v.z); s_hi[o + 2] = h; s_lo[o + 2] = f2bf(v.z - bf2f(h));
                    h = f2bf(v.w); s_hi[o + 3] = h; s_lo[o + 3] = f2bf(v.w - bf2f(h));
                }
            } else {
                #pragma unroll 1
                for (int e = tid; e < PATCH; e += 256) {
                    int pix = e / CB;
                    int icl = e - pix * CB;
                    int py = pix / PW;
                    int px = pix - py * PW;
                    int gic = chunk * CB + icl;
                    int xg = x0 + px;
                    float v = 0.0f;
                    if (gic < IC && xg < Win)
                        v = inI[((size_t)(y0 + py) * Win + xg) * IC + gic];
                    unsigned short h = f2bf(v);
                    s_hi[e] = h;
                    s_lo[e] = f2bf(v - bf2f(h));
                }
            }
            __syncthreads();

            // ----- MFMA over (ky, run) k-steps -----
            const unsigned short* BtC =
                Bt + (size_t)(chunk * K) * R * 2 * OCp * 32;
            #pragma unroll 1
            for (int ky = 0; ky < K; ++ky) {
                #pragma unroll
                for (int run = 0; run < R; ++run) {
                    const unsigned short* bp =
                        BtC + (size_t)((ky * R + run) * 2) * OCp * 32;
                    bf16x8 bh[NW], bl[NW];
                    #pragma unroll
                    for (int n = 0; n < NW; ++n) {
                        int ocl = (n * 16 + laneM) * 32 + laneK * 8;
                        bh[n] = *(const bf16x8*)(bp + ocl);
                        bl[n] = *(const bf16x8*)(bp + OCp * 32 + ocl);
                    }
                    #pragma unroll
                    for (int m = 0; m < 4; ++m) {
                        int py = wave * 2 + (m >> 1) + ky;
                        int off = (py * PW + (m & 1) * 16) * CB + run * 32 + laneA;
                        bf16x8 ah = *(const bf16x8*)&s_hi[off];
                        bf16x8 al = *(const bf16x8*)&s_lo[off];
                        #pragma unroll
                        for (int n = 0; n < NW; ++n) {
                            acc[m][n] = __builtin_amdgcn_mfma_f32_16x16x32_bf16(ah, bh[n], acc[m][n], 0, 0, 0);
                            acc[m][n] = __builtin_amdgcn_mfma_f32_16x16x32_bf16(ah, bl[n], acc[m][n], 0, 0, 0);
                            acc[m][n] = __builtin_amdgcn_mfma_f32_16x16x32_bf16(al, bh[n], acc[m][n], 0, 0, 0);
                        }
                    }
                }
            }
            __syncthreads();
        }

        // ----- epilogue: bias (+ReLU), store NHWC fp32 -----
        #pragma unroll
        for (int m = 0; m < 4; ++m) {
            int y = y0 + wave * 2 + (m >> 1);
            int xbase = x0 + (m & 1) * 16 + laneK * 4;
            #pragma unroll
            for (int n = 0; n < NW; ++n) {
                int oc = n * 16 + laneM;
                if (oc < OC) {
                    float bv = bias[oc];
                    float* op = outI + ((size_t)y * Wo + xbase) * OC + oc;
                    #pragma unroll
                    for (int r = 0; r < 4; ++r) {
                        float vv = acc[m][n][r] + bv;
                        if (RELU) vv = fmaxf(vv, 0.0f);
                        op[(size_t)r * OC] = vv;
                    }
                }
            }
        }
    }
}

// ---------------------------------------------------------------------------
// 1x1 conv (fp32, memory-bound): NHWC in -> NCHW out. No ReLU.
// ---------------------------------------------------------------------------
template<int NOUT>
__global__ __launch_bounds__(256) void conv1x1_kernel(
    const float* __restrict__ in, const float* __restrict__ w,
    const float* __restrict__ bias, float* __restrict__ out,
    int N, int IC, long inStride, long outStride)
{
    int px = blockIdx.x * 256 + threadIdx.x;
    int img = blockIdx.y;
    if (px >= N) return;
    const float* p = in + (size_t)img * inStride + (size_t)px * IC;
    float a[NOUT];
    #pragma unroll
    for (int o = 0; o < NOUT; ++o) a[o] = 0.0f;
    for (int ic = 0; ic < IC; ++ic) {
        float v = p[ic];
        #pragma unroll
        for (int o = 0; o < NOUT; ++o) a[o] = fmaf(v, w[o * IC + ic], a[o]);
    }
    #pragma unroll
    for (int o = 0; o < NOUT; ++o)
        out[(size_t)img * outStride + (size_t)o * N + px] = a[o] + bias[o];
}

// ---------------------------------------------------------------------------
// Bicubic warp: disp (1x256x256) + cf (22x256x256, NCHW) -> 15ch NHWC out.
// Arithmetic replicates the reference exactly (verified round 1).
// ---------------------------------------------------------------------------
__device__ __forceinline__ void cubicw(float t, float w[4])
{
    const float A = -0.75f;
    float u;
    u = t + 1.0f; w[0] = ((A * u - 5.0f * A) * u + 8.0f * A) * u - 4.0f * A;
    u = t;        w[1] = ((A + 2.0f) * u - (A + 3.0f)) * u * u + 1.0f;
    u = 1.0f - t; w[2] = ((A + 2.0f) * u - (A + 3.0f)) * u * u + 1.0f;
    u = 2.0f - t; w[3] = ((A * u - 5.0f * A) * u + 8.0f * A) * u - 4.0f * A;
}

__global__ __launch_bounds__(256) void warp_kernel(
    const float* __restrict__ disp, const float* __restrict__ cf,
    float* __restrict__ outw)
{
    const int P = 65536;
    int idx = blockIdx.x * 256 + threadIdx.x;
    int img = blockIdx.y;
    const float* dI  = disp + (size_t)img * P;
    const float* cfI = cf + (size_t)img * 22 * P;
    float* oI = outw + (size_t)img * 15 * P;

    int u = idx >> 8;
    int v = idx & 255;

    float d  = dI[idx];
    float q0 = cfI[20 * P + idx];
    float q1 = cfI[21 * P + idx];

    for (int i = 0; i < 4; ++i) {
        const float* img5 = cfI + (size_t)(5 * i) * P;
        float p0 = img5[3 * P + idx];
        float p1 = img5[4 * P + idx];
        float lr = (float)u + (p0 - q0) * d;
        float lc = (float)v + (p1 - q1) * d;
        float gr = (lr / 255.0f - 0.5f) * 2.0f;
        float gc = (lc / 255.0f - 0.5f) * 2.0f;
        float x = ((gc + 1.0f) * 256.0f - 1.0f) * 0.5f;
        float y = ((gr + 1.0f) * 256.0f - 1.0f) * 0.5f;
        float xf = floorf(x), yf = floorf(y);
        float tx = x - xf, tyy = y - yf;
        float wx[4], wy[4];
        cubicw(tx, wx);
        cubicw(tyy, wy);
        int xi = (int)xf, yi = (int)yf;
        float a0 = 0.f, a1 = 0.f, a2 = 0.f;
        #pragma unroll
        for (int ii = 0; ii < 4; ++ii) {
            int yy = yi - 1 + ii;
            bool vy = (yy >= 0) && (yy < 256);
            int yc = min(max(yy, 0), 255);
            #pragma unroll
            for (int jj = 0; jj < 4; ++jj) {
                int xx = xi - 1 + jj;
                bool vv = vy && (xx >= 0) && (xx < 256);
                int xc = min(max(xx, 0), 255);
                float w = vv ? wy[ii] * wx[jj] : 0.0f;
                int pos = yc * 256 + xc;
                a0 = fmaf(img5[pos], w, a0);
                a1 = fmaf(img5[P + pos], w, a1);
                a2 = fmaf(img5[2 * P + pos], w, a2);
            }
        }
        oI[(size_t)idx * 15 + 3 * i + 0] = a0;
        oI[(size_t)idx * 15 + 3 * i + 1] = a1;
        oI[(size_t)idx * 15 + 3 * i + 2] = a2;
    }
    oI[(size_t)idx * 15 + 12] = d;
    oI[(size_t)idx * 15 + 13] = q0;
    oI[(size_t)idx * 15 + 14] = q1;
}

// ---------------------------------------------------------------------------

extern "C" void kernel_launch(void* const* d_in, const int* in_sizes, int n_in,
                              void* d_out, int out_size, void* d_ws, size_t ws_size,
                              hipStream_t stream)
{
    const float* dF  = (const float*)d_in[0];
    const float* cF  = (const float*)d_in[1];
    const float* dw1 = (const float*)d_in[2];
    const float* db1 = (const float*)d_in[3];
    const float* dw2 = (const float*)d_in[4];
    const float* db2 = (const float*)d_in[5];
    const float* dw3 = (const float*)d_in[6];
    const float* db3 = (const float*)d_in[7];
    const float* dw4 = (const float*)d_in[8];
    const float* db4 = (const float*)d_in[9];
    const float* cw1 = (const float*)d_in[10];
    const float* cb1 = (const float*)d_in[11];
    const float* cw2 = (const float*)d_in[12];
    const float* cb2 = (const float*)d_in[13];
    const float* cw3 = (const float*)d_in[14];
    const float* cb3 = (const float*)d_in[15];
    const float* cw4 = (const float*)d_in[16];
    const float* cb4 = (const float*)d_in[17];

    float* outp = (float*)d_out;
    char* ws = (char*)d_ws;

    // transformed-weight region (bytes)
    const size_t SZ_D1 = (size_t)378 * 2 * 112 * 32 * 2;  // 5,419,008
    const size_t SZ_D2 = (size_t)100 * 2 * 112 * 32 * 2;  // 1,433,600
    const size_t SZ_D3 = (size_t)45  * 2 *  64 * 32 * 2;  //   368,640
    const size_t SZ_C1 = (size_t)42  * 2 * 112 * 32 * 2;  //   602,112
    const size_t O_D1 = 0;
    const size_t O_D2 = O_D1 + SZ_D1;
    const size_t O_D3 = O_D2 + SZ_D2;
    const size_t O_C1 = O_D3 + SZ_D3;
    const size_t O_C2 = O_C1 + SZ_C1;
    const size_t O_C3 = O_C2 + SZ_D2;
    const size_t O_END = O_C3 + SZ_D3;   // 9,625,600

    unsigned short* bt_d1 = (unsigned short*)(ws + O_D1);
    unsigned short* bt_d2 = (unsigned short*)(ws + O_D2);
    unsigned short* bt_d3 = (unsigned short*)(ws + O_D3);
    unsigned short* bt_c1 = (unsigned short*)(ws + O_C1);
    unsigned short* bt_c2 = (unsigned short*)(ws + O_C2);
    unsigned short* bt_c3 = (unsigned short*)(ws + O_C3);

    // weight transforms (cheap, once per call)
    auto T = [&](const float* w, unsigned short* bt, int IC, int OC, int OCp,
                 int K, int R, int ksteps) {
        int n = ksteps * OCp;
        wtrans_kernel<<<(n + 255) / 256, 256, 0, stream>>>(w, bt, IC, OC, OCp, K, R, ksteps);
    };
    T(dw1, bt_d1, 200, 100, 112, 7, 6, 9 * 7 * 6);
    T(dw2, bt_d2, 100, 100, 112, 5, 4, 5 * 5 * 4);
    T(dw3, bt_d3, 100,  50,  64, 3, 3, 5 * 3 * 3);
    T(cw1, bt_c1,  15, 100, 112, 7, 6, 1 * 7 * 6);
    T(cw2, bt_c2, 100, 100, 112, 5, 4, 5 * 5 * 4);
    T(cw3, bt_c3, 100,  50,  64, 3, 3, 5 * 3 * 3);

    const size_t perImgF = 6864400u + 6656400u + 65536u + 983040u;  // floats
    int batch = (ws_size >= O_END + 4u * perImgF * 4u + 4096u) ? 4 : 1;

    for (int g0 = 0; g0 < 4; g0 += batch) {
        float* actA = (float*)(ws + O_END);
        float* actB = actA + (size_t)6864400 * batch;
        float* disp = actB + (size_t)6656400 * batch;
        float* wrp  = disp + (size_t)65536 * batch;
        const float* dFg = dF + (size_t)g0 * 200 * 268 * 268;
        const float* cFg = cF + (size_t)g0 * 22 * 65536;
        float* outg = outp + (size_t)g0 * 3 * 59536;

        // disparity net
        conv_mfma<7, 7, true,  true><<<512, 256, 0, stream>>>(
            dFg, bt_d1, db1, actA, 268, 268, 200, 100, 262, 262, 9, 9, 33, batch,
            14364800L, 6864400L);
        conv_mfma<5, 7, false, true><<<512, 256, 0, stream>>>(
            actA, bt_d2, db2, actB, 262, 262, 100, 100, 258, 258, 5, 9, 33, batch,
            6864400L, 6656400L);
        conv_mfma<3, 4, false, true><<<512, 256, 0, stream>>>(
            actB, bt_d3, db3, actA, 258, 258, 100, 50, 256, 256, 5, 8, 32, batch,
            6656400L, 3276800L);
        conv1x1_kernel<1><<<dim3(256, batch), 256, 0, stream>>>(
            actA, dw4, db4, disp, 65536, 50, 3276800L, 65536L);

        // warp
        warp_kernel<<<dim3(256, batch), 256, 0, stream>>>(disp, cFg, wrp);

        // color net
        conv_mfma<7, 7, false, true><<<512, 256, 0, stream>>>(
            wrp, bt_c1, cb1, actB, 256, 256, 15, 100, 250, 250, 1, 8, 32, batch,
            983040L, 6250000L);
        conv_mfma<5, 7, false, true><<<512, 256, 0, stream>>>(
            actB, bt_c2, cb2, actA, 250, 250, 100, 100, 246, 246, 5, 8, 31, batch,
            6250000L, 6051600L);
        conv_mfma<3, 4, false, true><<<512, 256, 0, stream>>>(
            actA, bt_c3, cb3, actB, 246, 246, 100, 50, 244, 244, 5, 8, 31, batch,
            6051600L, 2976800L);
        conv1x1_kernel<3><<<dim3(233, batch), 256, 0, stream>>>(
            actB, cw4, cb4, outg, 59536, 50, 2976800L, 178608L);
    }
}

// Round 3
// 2537.406 us; speedup vs baseline: 8.0390x; 2.0050x over previous
//
#include <hip/hip_runtime.h>
#include <cstddef>
#include <cstdint>

typedef _Float16 f16x8 __attribute__((ext_vector_type(8)));
typedef float f32x4 __attribute__((ext_vector_type(4)));

// ---------------------------------------------------------------------------
// Weight transform: OIHW fp32 -> Bt[kstep][OCp][32] fp16.
// kstep = (chunk*K + ky)*R + run ; slot j: flat = run*32+j -> x_off = flat/24,
// ic = chunk*24 + flat%24. Zero for oc>=OC, ic>=IC, x_off>=K.
// ---------------------------------------------------------------------------
__global__ __launch_bounds__(256) void wtrans_kernel(
    const float* __restrict__ w, _Float16* __restrict__ Bt,
    int IC, int OC, int OCp, int K, int R, int ksteps)
{
    int gid = blockIdx.x * 256 + threadIdx.x;
    if (gid >= ksteps * OCp) return;
    int ks = gid / OCp;
    int oc = gid - ks * OCp;
    int run = ks % R;
    int t2 = ks / R;
    int ky = t2 % K;
    int chunk = t2 / K;
    _Float16* p = Bt + ((size_t)ks * OCp + oc) * 32;
    for (int j = 0; j < 32; ++j) {
        int flat = run * 32 + j;
        int xo = flat / 24;
        int icl = flat - xo * 24;
        int ic = chunk * 24 + icl;
        float v = 0.0f;
        if (oc < OC && ic < IC && xo < K)
            v = w[(((size_t)oc * IC + ic) * K + ky) * K + xo];
        p[j] = (_Float16)v;
    }
}

// ---------------------------------------------------------------------------
// Input pre-convert: NCHW fp32 (200ch, 268x268) -> chunked fp16
// [img][9][268][268*24]. Transpose through LDS, coalesced both sides.
// ---------------------------------------------------------------------------
__global__ __launch_bounds__(256) void convin_kernel(
    const float* __restrict__ src, _Float16* __restrict__ dst, int IC)
{
    constexpr int W = 268;
    constexpr int PADS = 273;          // odd stride -> conflict-light
    __shared__ float s[24 * PADS];
    int y = blockIdx.x, chunk = blockIdx.y, img = blockIdx.z;
    int tid = threadIdx.x;
    for (int e = tid; e < 24 * W; e += 256) {
        int icl = e / W;
        int x = e - icl * W;
        int ic = chunk * 24 + icl;
        float v = 0.0f;
        if (ic < IC)
            v = src[(((size_t)img * IC + ic) * W + y) * W + x];
        s[icl * PADS + x] = v;
    }
    __syncthreads();
    _Float16* outRow = dst + ((size_t)(img * 9 + chunk) * W + y) * (W * 24);
    for (int u = tid; u < W * 3; u += 256) {      // 3 x 16B units per pixel
        int px = u / 3;
        int sub = u - px * 3;
        f16x8 t;
        #pragma unroll
        for (int j = 0; j < 8; ++j)
            t[j] = (_Float16)s[(sub * 8 + j) * PADS + px];
        ((f16x8*)outRow)[u] = t;
    }
}

// ---------------------------------------------------------------------------
// Implicit-GEMM conv, MFMA 16x16x32 fp16 (single, no split).
// Input: chunked fp16 [chunk][Hin][Win*24]. Output: chunked fp16.
// Block 256 = 4 waves; wave: 4 m-tiles (2y x 2xhalf) x NW n-tiles.
// A staged per-chunk in LDS via contiguous 16B row copies (clamped; the
// clamped tail slots only feed zero-B taps). B read from global (L1/L2).
// ---------------------------------------------------------------------------
template<int K, int NW, bool RELU>
__global__ __launch_bounds__(256, 2) void conv_mfma(
    const _Float16* __restrict__ in, const _Float16* __restrict__ Bt,
    const float* __restrict__ bias, _Float16* __restrict__ out,
    int Hin, int Win, int OC, int Ho, int Wo,
    int nchunks, int xb, int yb, int nimg,
    long inStride, long outStride)
{
    constexpr int CB = 24;
    constexpr int R  = (K * CB + 31) / 32;
    constexpr int PH = 8 + K - 1;
    constexpr int PW = 32 + (R * 32 - 1) / CB + 1;
    constexpr int OCp = NW * 16;
    constexpr int UROW = PW * 3;           // 16B units per staged row
    constexpr int UTOT = PH * UROW;

    __shared__ __align__(16) _Float16 s_in[PH * PW * CB];

    const int tid   = threadIdx.x;
    const int lane  = tid & 63;
    const int wave  = tid >> 6;
    const int laneM = lane & 15;
    const int laneK = lane >> 4;
    const int rowE  = Win * 24;

    const int tilesPerImg = xb * yb;
    const int totTiles = tilesPerImg * nimg;

    #pragma unroll 1
    for (int t = blockIdx.x; t < totTiles; t += gridDim.x) {
        int img = t / tilesPerImg;
        int rem = t - img * tilesPerImg;
        int byi = rem / xb;
        int bxi = rem - byi * xb;
        int y0 = byi * 8;  if (y0 > Ho - 8)  y0 = Ho - 8;
        int x0 = bxi * 32; if (x0 > Wo - 32) x0 = Wo - 32;

        const _Float16* inI = in + (size_t)img * inStride;
        _Float16* outI = out + (size_t)img * outStride;

        f32x4 acc[4][NW];
        #pragma unroll
        for (int m = 0; m < 4; ++m)
            #pragma unroll
            for (int n = 0; n < NW; ++n)
                acc[m][n] = (f32x4){0.f, 0.f, 0.f, 0.f};

        #pragma unroll 1
        for (int chunk = 0; chunk < nchunks; ++chunk) {
            const _Float16* inC = inI + (size_t)chunk * Hin * rowE;
            const int mx = rowE - 8;
            #pragma unroll 1
            for (int e = tid; e < UTOT; e += 256) {
                int py = e / UROW;
                int uu = e - py * UROW;
                int off = x0 * 24 + uu * 8;
                if (off > mx) off = mx;   // clamped slots feed zero-B taps
                uint4 val = *(const uint4*)(inC + (size_t)(y0 + py) * rowE + off);
                *(uint4*)&s_in[(size_t)e * 8] = val;
            }
            __syncthreads();

            const _Float16* BtC = Bt + (size_t)(chunk * K) * R * OCp * 32;
            #pragma unroll 1
            for (int ky = 0; ky < K; ++ky) {
                #pragma unroll
                for (int run = 0; run < R; ++run) {
                    const _Float16* bp = BtC + (size_t)(ky * R + run) * OCp * 32;
                    f16x8 b[NW];
                    #pragma unroll
                    for (int n = 0; n < NW; ++n)
                        b[n] = *(const f16x8*)(bp + (n * 16 + laneM) * 32 + laneK * 8);
                    #pragma unroll
                    for (int m = 0; m < 4; ++m) {
                        int py = wave * 2 + (m >> 1) + ky;
                        int off = (py * PW + (m & 1) * 16 + laneM) * CB + run * 32 + laneK * 8;
                        f16x8 a = *(const f16x8*)&s_in[off];
                        #pragma unroll
                        for (int n = 0; n < NW; ++n)
                            acc[m][n] = __builtin_amdgcn_mfma_f32_16x16x32_f16(a, b[n], acc[m][n], 0, 0, 0);
                    }
                }
            }
            __syncthreads();
        }

        // epilogue: bias (+ReLU), store chunked fp16 [oc/24][y][x*24 + oc%24]
        #pragma unroll
        for (int n = 0; n < NW; ++n) {
            int oc = n * 16 + laneM;
            if (oc < OC) {
                float bv = bias[oc];
                int icc = oc / 24;
                int ocl = oc - icc * 24;
                #pragma unroll
                for (int m = 0; m < 4; ++m) {
                    int y = y0 + wave * 2 + (m >> 1);
                    int xb2 = x0 + (m & 1) * 16 + laneK * 4;
                    _Float16* op = outI + ((size_t)icc * Ho + y) * (Wo * 24) + xb2 * 24 + ocl;
                    #pragma unroll
                    for (int r = 0; r < 4; ++r) {
                        float vv = acc[m][n][r] + bv;
                        if (RELU) vv = fmaxf(vv, 0.0f);
                        op[(size_t)r * 24] = (_Float16)vv;
                    }
                }
            }
        }
    }
}

// ---------------------------------------------------------------------------
// 1x1 conv: chunked fp16 in -> NCHW fp32 out. No ReLU.
// ---------------------------------------------------------------------------
template<int NOUT>
__global__ __launch_bounds__(256) void conv1x1_kernel(
    const _Float16* __restrict__ in, const float* __restrict__ w,
    const float* __restrict__ bias, float* __restrict__ out,
    int N, int IC, long inStride, long outStride)
{
    int px = blockIdx.x * 256 + threadIdx.x;
    int img = blockIdx.y;
    if (px >= N) return;
    const _Float16* p = in + (size_t)img * inStride;
    float a[NOUT];
    #pragma unroll
    for (int o = 0; o < NOUT; ++o) a[o] = 0.0f;
    for (int ic = 0; ic < IC; ++ic) {
        int icc = ic / 24;
        int icl = ic - icc * 24;
        float v = (float)p[((size_t)icc * N + px) * 24 + icl];
        #pragma unroll
        for (int o = 0; o < NOUT; ++o) a[o] = fmaf(v, w[o * IC + ic], a[o]);
    }
    #pragma unroll
    for (int o = 0; o < NOUT; ++o)
        out[(size_t)img * outStride + (size_t)o * N + px] = a[o] + bias[o];
}

// ---------------------------------------------------------------------------
// Bicubic warp: disp fp32 + cf fp32 (NCHW) -> chunked fp16 (1 chunk, 15 ch
// used, 15..23 zeroed). Arithmetic replicates reference (verified R1/R2).
// ---------------------------------------------------------------------------
__device__ __forceinline__ void cubicw(float t, float w[4])
{
    const float A = -0.75f;
    float u;
    u = t + 1.0f; w[0] = ((A * u - 5.0f * A) * u + 8.0f * A) * u - 4.0f * A;
    u = t;        w[1] = ((A + 2.0f) * u - (A + 3.0f)) * u * u + 1.0f;
    u = 1.0f - t; w[2] = ((A + 2.0f) * u - (A + 3.0f)) * u * u + 1.0f;
    u = 2.0f - t; w[3] = ((A * u - 5.0f * A) * u + 8.0f * A) * u - 4.0f * A;
}

__global__ __launch_bounds__(256) void warp_kernel(
    const float* __restrict__ disp, const float* __restrict__ cf,
    _Float16* __restrict__ outw)
{
    const int P = 65536;
    int idx = blockIdx.x * 256 + threadIdx.x;
    int img = blockIdx.y;
    const float* dI  = disp + (size_t)img * P;
    const float* cfI = cf + (size_t)img * 22 * P;
    _Float16* oI = outw + (size_t)img * 1572864 + (size_t)idx * 24;

    int u = idx >> 8;
    int v = idx & 255;

    float d  = dI[idx];
    float q0 = cfI[20 * P + idx];
    float q1 = cfI[21 * P + idx];

    for (int i = 0; i < 4; ++i) {
        const float* img5 = cfI + (size_t)(5 * i) * P;
        float p0 = img5[3 * P + idx];
        float p1 = img5[4 * P + idx];
        float lr = (float)u + (p0 - q0) * d;
        float lc = (float)v + (p1 - q1) * d;
        float gr = (lr / 255.0f - 0.5f) * 2.0f;
        float gc = (lc / 255.0f - 0.5f) * 2.0f;
        float x = ((gc + 1.0f) * 256.0f - 1.0f) * 0.5f;
        float y = ((gr + 1.0f) * 256.0f - 1.0f) * 0.5f;
        float xf = floorf(x), yf = floorf(y);
        float tx = x - xf, tyy = y - yf;
        float wx[4], wy[4];
        cubicw(tx, wx);
        cubicw(tyy, wy);
        int xi = (int)xf, yi = (int)yf;
        float a0 = 0.f, a1 = 0.f, a2 = 0.f;
        #pragma unroll
        for (int ii = 0; ii < 4; ++ii) {
            int yy = yi - 1 + ii;
            bool vy = (yy >= 0) && (yy < 256);
            int yc = min(max(yy, 0), 255);
            #pragma unroll
            for (int jj = 0; jj < 4; ++jj) {
                int xx = xi - 1 + jj;
                bool vv = vy && (xx >= 0) && (xx < 256);
                int xc = min(max(xx, 0), 255);
                float w = vv ? wy[ii] * wx[jj] : 0.0f;
                int pos = yc * 256 + xc;
                a0 = fmaf(img5[pos], w, a0);
                a1 = fmaf(img5[P + pos], w, a1);
                a2 = fmaf(img5[2 * P + pos], w, a2);
            }
        }
        oI[3 * i + 0] = (_Float16)a0;
        oI[3 * i + 1] = (_Float16)a1;
        oI[3 * i + 2] = (_Float16)a2;
    }
    oI[12] = (_Float16)d;
    oI[13] = (_Float16)q0;
    oI[14] = (_Float16)q1;
    #pragma unroll
    for (int c = 15; c < 24; ++c) oI[c] = (_Float16)0.0f;
}

// ---------------------------------------------------------------------------

extern "C" void kernel_launch(void* const* d_in, const int* in_sizes, int n_in,
                              void* d_out, int out_size, void* d_ws, size_t ws_size,
                              hipStream_t stream)
{
    const float* dF  = (const float*)d_in[0];
    const float* cF  = (const float*)d_in[1];
    const float* dw1 = (const float*)d_in[2];
    const float* db1 = (const float*)d_in[3];
    const float* dw2 = (const float*)d_in[4];
    const float* db2 = (const float*)d_in[5];
    const float* dw3 = (const float*)d_in[6];
    const float* db3 = (const float*)d_in[7];
    const float* dw4 = (const float*)d_in[8];
    const float* db4 = (const float*)d_in[9];
    const float* cw1 = (const float*)d_in[10];
    const float* cb1 = (const float*)d_in[11];
    const float* cw2 = (const float*)d_in[12];
    const float* cb2 = (const float*)d_in[13];
    const float* cw3 = (const float*)d_in[14];
    const float* cb3 = (const float*)d_in[15];
    const float* cw4 = (const float*)d_in[16];
    const float* cb4 = (const float*)d_in[17];

    float* outp = (float*)d_out;
    char* ws = (char*)d_ws;

    // ---- transformed-weight region (fp16) ----
    const size_t O_D1 = 0;                       // 378*112*32*2 = 2,709,504
    const size_t O_D2 = O_D1 + 2709504;          // 100*112*32*2 =   716,800
    const size_t O_D3 = O_D2 + 716800;           //  45* 64*32*2 =   184,320
    const size_t O_C1 = O_D3 + 184320;           //  42*112*32*2 =   301,056
    const size_t O_C2 = O_C1 + 301056;           //   716,800
    const size_t O_C3 = O_C2 + 716800;           //   184,320
    const size_t O_WEND = O_C3 + 184320;         // 4,812,800

    _Float16* bt_d1 = (_Float16*)(ws + O_D1);
    _Float16* bt_d2 = (_Float16*)(ws + O_D2);
    _Float16* bt_d3 = (_Float16*)(ws + O_D3);
    _Float16* bt_c1 = (_Float16*)(ws + O_C1);
    _Float16* bt_c2 = (_Float16*)(ws + O_C2);
    _Float16* bt_c3 = (_Float16*)(ws + O_C3);

    auto T = [&](const float* w, _Float16* bt, int IC, int OC, int OCp,
                 int K, int R, int ksteps) {
        int n = ksteps * OCp;
        wtrans_kernel<<<(n + 255) / 256, 256, 0, stream>>>(w, bt, IC, OC, OCp, K, R, ksteps);
    };
    T(dw1, bt_d1, 200, 100, 112, 7, 6, 9 * 7 * 6);
    T(dw2, bt_d2, 100, 100, 112, 5, 4, 5 * 5 * 4);
    T(dw3, bt_d3, 100,  50,  64, 3, 3, 5 * 3 * 3);
    T(cw1, bt_c1,  15, 100, 112, 7, 6, 1 * 7 * 6);
    T(cw2, bt_c2, 100, 100, 112, 5, 4, 5 * 5 * 4);
    T(cw3, bt_c3, 100,  50,  64, 3, 3, 5 * 3 * 3);

    // ---- activation regions (per batch-group of N images) ----
    // dFc: 31,027,968 B/img ; bufA: 16,474,560 ; bufB: 15,975,360
    // aliased into dFc (dead after d1): bufC 9,437,184 ; disp 262,144 ; wrp 3,145,728
    const size_t PER_IMG = 31027968ull + 16474560ull + 15975360ull; // 63,477,888
    int batch = (ws_size >= O_WEND + 4ull * PER_IMG + 1024) ? 4
              : (ws_size >= O_WEND + 2ull * PER_IMG + 1024) ? 2 : 1;

    for (int g0 = 0; g0 < 4; g0 += batch) {
        const int N = batch;
        char* p = ws + O_WEND;
        _Float16* dFc  = (_Float16*)p;
        _Float16* bufA = (_Float16*)(p + 31027968ull * N);
        _Float16* bufB = (_Float16*)(p + (31027968ull + 16474560ull) * N);
        _Float16* bufC = (_Float16*)p;                       // alias dFc
        float*    disp = (float*)(p + 9437184ull * N);       // alias dFc
        _Float16* wrp  = (_Float16*)(p + 9699328ull * N);    // alias dFc

        const float* dFg = dF + (size_t)g0 * 200 * 268 * 268;
        const float* cFg = cF + (size_t)g0 * 22 * 65536;
        float* outg = outp + (size_t)g0 * 3 * 59536;

        convin_kernel<<<dim3(268, 9, N), 256, 0, stream>>>(dFg, dFc, 200);

        // disparity net
        conv_mfma<7, 7, true><<<512, 256, 0, stream>>>(
            dFc, bt_d1, db1, bufA, 268, 268, 100, 262, 262, 9, 9, 33, N,
            15513984L, 8237280L);
        conv_mfma<5, 7, true><<<512, 256, 0, stream>>>(
            bufA, bt_d2, db2, bufB, 262, 262, 100, 258, 258, 5, 9, 33, N,
            8237280L, 7987680L);
        conv_mfma<3, 4, true><<<512, 256, 0, stream>>>(
            bufB, bt_d3, db3, bufC, 258, 258, 50, 256, 256, 5, 8, 32, N,
            7987680L, 4718592L);
        conv1x1_kernel<1><<<dim3(256, N), 256, 0, stream>>>(
            bufC, dw4, db4, disp, 65536, 50, 4718592L, 65536L);

        // warp
        warp_kernel<<<dim3(256, N), 256, 0, stream>>>(disp, cFg, wrp);

        // color net
        conv_mfma<7, 7, true><<<512, 256, 0, stream>>>(
            wrp, bt_c1, cb1, bufA, 256, 256, 100, 250, 250, 1, 8, 32, N,
            1572864L, 8237280L);
        conv_mfma<5, 7, true><<<512, 256, 0, stream>>>(
            bufA, bt_c2, cb2, bufB, 250, 250, 100, 246, 246, 5, 8, 31, N,
            8237280L, 7987680L);
        conv_mfma<3, 4, true><<<512, 256, 0, stream>>>(
            bufB, bt_c3, cb3, bufC, 246, 246, 50, 244, 244, 5, 8, 31, N,
            7987680L, 4718592L);
        conv1x1_kernel<3><<<dim3(233, N), 256, 0, stream>>>(
            bufC, cw4, cb4, outg, 59536, 50, 4718592L, 178608L);
    }
}

// Round 4
// 1804.157 us; speedup vs baseline: 11.3062x; 1.4064x over previous
//
#include <hip/hip_runtime.h>
#include <cstddef>
#include <cstdint>

typedef _Float16 f16x8 __attribute__((ext_vector_type(8)));
typedef _Float16 f16x4 __attribute__((ext_vector_type(4)));
typedef float    f32x16 __attribute__((ext_vector_type(16)));

// ---------------------------------------------------------------------------
// Weight transform: OIHW fp32 -> Bt[kstep][g][lane][8j] fp16 (frag-native for
// mfma_f32_32x32x16_f16 B operand: n = lane&31, k = (lane>>5)*8 + j).
// kstep = (chunk*K + ky)*R + run; flat = run*16 + k; x_off = flat/20,
// ic = chunk*20 + flat%20. Zero for oc>=OC, ic>=IC, x_off>=K.
// ---------------------------------------------------------------------------
__global__ __launch_bounds__(256) void wtrans_kernel(
    const float* __restrict__ w, _Float16* __restrict__ Bt,
    int IC, int OC, int G, int K, int R, int ksteps)
{
    int gid = blockIdx.x * 256 + threadIdx.x;
    if (gid >= ksteps * G * 64) return;
    int ks   = gid / (G * 64);
    int rr   = gid - ks * G * 64;
    int g    = rr >> 6;
    int lane = rr & 63;
    int run = ks % R;
    int t2  = ks / R;
    int ky  = t2 % K;
    int chunk = t2 / K;
    int oc = g * 32 + (lane & 31);
    int kh = lane >> 5;
    _Float16 tmp[8];
    #pragma unroll
    for (int j = 0; j < 8; ++j) {
        int flat = run * 16 + kh * 8 + j;
        int xo  = flat / 20;
        int icl = flat - xo * 20;
        int ic  = chunk * 20 + icl;
        float v = 0.0f;
        if (oc < OC && ic < IC && xo < K)
            v = w[(((size_t)oc * IC + ic) * K + ky) * K + xo];
        tmp[j] = (_Float16)v;
    }
    *(uint4*)(Bt + (size_t)gid * 8) = *(uint4*)tmp;
}

// ---------------------------------------------------------------------------
// Input pre-convert: NCHW fp32 (200ch) -> chunked fp16 [img][10][268][268*20].
// ---------------------------------------------------------------------------
__global__ __launch_bounds__(256) void convin_kernel(
    const float* __restrict__ src, _Float16* __restrict__ dst, int IC)
{
    constexpr int W = 268;
    constexpr int PADS = 272;
    __shared__ float s[20 * PADS];
    int y = blockIdx.x, chunk = blockIdx.y, img = blockIdx.z;
    int tid = threadIdx.x;
    for (int e = tid; e < 20 * W; e += 256) {
        int icl = e / W;
        int x = e - icl * W;
        int ic = chunk * 20 + icl;
        float v = 0.0f;
        if (ic < IC)
            v = src[(((size_t)img * IC + ic) * W + y) * W + x];
        s[icl * PADS + x] = v;
    }
    __syncthreads();
    _Float16* outRow = dst + ((size_t)(img * 10 + chunk) * W + y) * (W * 20);
    for (int u = tid; u < W * 20 / 8; u += 256) {
        _Float16 t[8];
        #pragma unroll
        for (int q = 0; q < 8; ++q) {
            int e = u * 8 + q;
            int px = e / 20;
            int c  = e - px * 20;
            t[q] = (_Float16)s[c * PADS + px];
        }
        *(uint4*)(outRow + (size_t)u * 8) = *(uint4*)t;
    }
}

// ---------------------------------------------------------------------------
// Implicit-GEMM conv, MFMA 32x32x16 fp16.
// Block: 8*WM/2-ish -> BM = WM*4 y-rows x 32 px x OCp (WN*64) oc; 4 waves:
//   WN==2: wm=wave&1 (y-half), wn=wave>>1 (oc-half); WN==1: wm=wave, wn=0.
// Wave: 4 m-tiles (y-rows) x 2 n-tiles (32 oc). A staged per-20ch-chunk in
// LDS (contiguous 16B row copies); B frag-native from global (L2-resident).
// m-tile = 1 y-row x 32 x; A lane: m=lane&31 (x), k=(lane>>5)*8+j.
// C/D: col(n)=lane&31, row(x)=(reg&3)+8*(reg>>2)+4*(lane>>5).
// ---------------------------------------------------------------------------
template<int K, int WM, int WN, bool RELU>
__global__ __launch_bounds__(256, 2) void conv_mfma(
    const _Float16* __restrict__ in, const _Float16* __restrict__ Bt,
    const float* __restrict__ bias, _Float16* __restrict__ out,
    int Hin, int Win, int OC, int Ho, int Wo,
    int nchunks, int xb, int tilesPerImg,
    long inStride, long outStride)
{
    constexpr int CB = 20;
    constexpr int R  = (K * CB + 15) / 16;
    constexpr int BM = WM * 4;
    constexpr int PH = BM + K - 1;
    constexpr int MAXF = 31 * CB + R * 16;
    constexpr int PW = (((MAXF + CB - 1) / CB) + 1) & ~1;
    constexpr int ROWF = PW * CB;          // f16 per LDS row
    constexpr int UROW = ROWF / 8;         // 16B units per row
    constexpr int G    = WN * 2;           // oc32-groups per kstep
    constexpr int KSF  = G * 512;          // f16 per kstep in Bt

    __shared__ __align__(16) _Float16 s[PH * ROWF];

    const int tid  = threadIdx.x;
    const int lane = tid & 63;
    const int wave = tid >> 6;
    const int wm   = (WN == 2) ? (wave & 1) : wave;
    const int wn   = (WN == 2) ? (wave >> 1) : 0;
    const int mcol = lane & 31;
    const int kh   = lane >> 5;
    const int alane = mcol * CB + kh * 8;

    int t = blockIdx.x;
    int img = t / tilesPerImg;
    int rem = t - img * tilesPerImg;
    int byi = rem / xb;
    int bxi = rem - byi * xb;
    int y0 = byi * BM; if (y0 > Ho - BM) y0 = Ho - BM;
    int x0 = bxi * 32; if (x0 > Wo - 32) x0 = Wo - 32;

    const _Float16* inI = in + (size_t)img * inStride;

    f32x16 acc[4][2];
    #pragma unroll
    for (int m = 0; m < 4; ++m)
        #pragma unroll
        for (int n = 0; n < 2; ++n)
            acc[m][n] = (f32x16)(0.0f);

    const int rowE = Win * CB;
    const int mxo  = rowE - 8;
    const size_t chStride = (size_t)Hin * rowE;

    #pragma unroll 1
    for (int chunk = 0; chunk < nchunks; ++chunk) {
        // ---- stage A patch (contiguous 16B units per row, clamped) ----
        const _Float16* inC = inI + chunk * chStride + (size_t)y0 * rowE;
        #pragma unroll 1
        for (int e = tid; e < PH * UROW; e += 256) {
            int py = e / UROW;
            int uu = e - py * UROW;
            int off = x0 * CB + uu * 8;
            if (off > mxo) off = mxo;     // clamped slots only feed zero-B taps
            uint4 val = *(const uint4*)(inC + (size_t)py * rowE + off);
            *(uint4*)&s[(size_t)e * 8] = val;
        }
        __syncthreads();

        const _Float16* BtC = Bt + (size_t)(chunk * K) * R * KSF;
        #pragma unroll 1
        for (int ky = 0; ky < K; ++ky) {
            const _Float16* BtK = BtC + (size_t)(ky * R) * KSF;
            const int rbase = (wm * 4 + ky) * ROWF + alane;
            #pragma unroll
            for (int run = 0; run < R; ++run) {
                const _Float16* bp = BtK + (size_t)run * KSF + (wn * 128 + lane) * 8;
                f16x8 b0 = *(const f16x8*)bp;
                f16x8 b1 = *(const f16x8*)(bp + 512);
                const int ab = rbase + run * 16;
                #pragma unroll
                for (int mt = 0; mt < 4; ++mt) {
                    const _Float16* ap = &s[ab + mt * ROWF];
                    f16x4 lo = *(const f16x4*)ap;
                    f16x4 hi = *(const f16x4*)(ap + 4);
                    f16x8 a = __builtin_shufflevector(lo, hi, 0, 1, 2, 3, 4, 5, 6, 7);
                    acc[mt][0] = __builtin_amdgcn_mfma_f32_32x32x16_f16(a, b0, acc[mt][0], 0, 0, 0);
                    acc[mt][1] = __builtin_amdgcn_mfma_f32_32x32x16_f16(a, b1, acc[mt][1], 0, 0, 0);
                }
            }
        }
        __syncthreads();
    }

    // ---- epilogue: bias (+ReLU), store chunked fp16 [oc/20][y][x*20+oc%20] ----
    _Float16* outI = out + (size_t)img * outStride;
    #pragma unroll
    for (int nt = 0; nt < 2; ++nt) {
        int oc = (wn * 2 + nt) * 32 + mcol;
        if (oc < OC) {
            float bv = bias[oc];
            int icc = oc / 20;
            int occ = oc - icc * 20;
            _Float16* base = outI + (size_t)icc * Ho * (Wo * 20) + occ;
            #pragma unroll
            for (int mt = 0; mt < 4; ++mt) {
                int y = y0 + wm * 4 + mt;
                _Float16* rowp = base + (size_t)y * (Wo * 20);
                #pragma unroll
                for (int reg = 0; reg < 16; ++reg) {
                    int x = x0 + (reg & 3) + 8 * (reg >> 2) + 4 * kh;
                    float v = acc[mt][nt][reg] + bv;
                    if (RELU) v = fmaxf(v, 0.0f);
                    rowp[(size_t)x * 20] = (_Float16)v;
                }
            }
        }
    }
}

// ---------------------------------------------------------------------------
// 1x1 conv: chunked-20 fp16 in -> NCHW fp32 out. No ReLU.
// ---------------------------------------------------------------------------
template<int NOUT>
__global__ __launch_bounds__(256) void conv1x1_kernel(
    const _Float16* __restrict__ in, const float* __restrict__ w,
    const float* __restrict__ bias, float* __restrict__ out,
    int N, int IC, long inStride, long outStride)
{
    int px = blockIdx.x * 256 + threadIdx.x;
    int img = blockIdx.y;
    if (px >= N) return;
    const _Float16* p = in + (size_t)img * inStride;
    float a[NOUT];
    #pragma unroll
    for (int o = 0; o < NOUT; ++o) a[o] = 0.0f;
    for (int ic = 0; ic < IC; ++ic) {
        int icc = ic / 20;
        int icl = ic - icc * 20;
        float v = (float)p[((size_t)icc * N + px) * 20 + icl];
        #pragma unroll
        for (int o = 0; o < NOUT; ++o) a[o] = fmaf(v, w[o * IC + ic], a[o]);
    }
    #pragma unroll
    for (int o = 0; o < NOUT; ++o)
        out[(size_t)img * outStride + (size_t)o * N + px] = a[o] + bias[o];
}

// ---------------------------------------------------------------------------
// Bicubic warp: disp fp32 + cf fp32 (NCHW) -> chunked-20 fp16 (ch 15..19 = 0).
// Arithmetic replicates reference (verified R1-R3).
// ---------------------------------------------------------------------------
__device__ __forceinline__ void cubicw(float t, float w[4])
{
    const float A = -0.75f;
    float u;
    u = t + 1.0f; w[0] = ((A * u - 5.0f * A) * u + 8.0f * A) * u - 4.0f * A;
    u = t;        w[1] = ((A + 2.0f) * u - (A + 3.0f)) * u * u + 1.0f;
    u = 1.0f - t; w[2] = ((A + 2.0f) * u - (A + 3.0f)) * u * u + 1.0f;
    u = 2.0f - t; w[3] = ((A * u - 5.0f * A) * u + 8.0f * A) * u - 4.0f * A;
}

__global__ __launch_bounds__(256) void warp_kernel(
    const float* __restrict__ disp, const float* __restrict__ cf,
    _Float16* __restrict__ outw)
{
    const int P = 65536;
    int idx = blockIdx.x * 256 + threadIdx.x;
    int img = blockIdx.y;
    const float* dI  = disp + (size_t)img * P;
    const float* cfI = cf + (size_t)img * 22 * P;
    _Float16* oI = outw + (size_t)img * 1310720 + (size_t)idx * 20;

    int u = idx >> 8;
    int v = idx & 255;

    float d  = dI[idx];
    float q0 = cfI[20 * P + idx];
    float q1 = cfI[21 * P + idx];

    for (int i = 0; i < 4; ++i) {
        const float* img5 = cfI + (size_t)(5 * i) * P;
        float p0 = img5[3 * P + idx];
        float p1 = img5[4 * P + idx];
        float lr = (float)u + (p0 - q0) * d;
        float lc = (float)v + (p1 - q1) * d;
        float gr = (lr / 255.0f - 0.5f) * 2.0f;
        float gc = (lc / 255.0f - 0.5f) * 2.0f;
        float x = ((gc + 1.0f) * 256.0f - 1.0f) * 0.5f;
        float y = ((gr + 1.0f) * 256.0f - 1.0f) * 0.5f;
        float xf = floorf(x), yf = floorf(y);
        float tx = x - xf, tyy = y - yf;
        float wx[4], wy[4];
        cubicw(tx, wx);
        cubicw(tyy, wy);
        int xi = (int)xf, yi = (int)yf;
        float a0 = 0.f, a1 = 0.f, a2 = 0.f;
        #pragma unroll
        for (int ii = 0; ii < 4; ++ii) {
            int yy = yi - 1 + ii;
            bool vy = (yy >= 0) && (yy < 256);
            int yc = min(max(yy, 0), 255);
            #pragma unroll
            for (int jj = 0; jj < 4; ++jj) {
                int xx = xi - 1 + jj;
                bool vv = vy && (xx >= 0) && (xx < 256);
                int xc = min(max(xx, 0), 255);
                float w = vv ? wy[ii] * wx[jj] : 0.0f;
                int pos = yc * 256 + xc;
                a0 = fmaf(img5[pos], w, a0);
                a1 = fmaf(img5[P + pos], w, a1);
                a2 = fmaf(img5[2 * P + pos], w, a2);
            }
        }
        oI[3 * i + 0] = (_Float16)a0;
        oI[3 * i + 1] = (_Float16)a1;
        oI[3 * i + 2] = (_Float16)a2;
    }
    oI[12] = (_Float16)d;
    oI[13] = (_Float16)q0;
    oI[14] = (_Float16)q1;
    #pragma unroll
    for (int c = 15; c < 20; ++c) oI[c] = (_Float16)0.0f;
}

// ---------------------------------------------------------------------------

extern "C" void kernel_launch(void* const* d_in, const int* in_sizes, int n_in,
                              void* d_out, int out_size, void* d_ws, size_t ws_size,
                              hipStream_t stream)
{
    const float* dF  = (const float*)d_in[0];
    const float* cF  = (const float*)d_in[1];
    const float* dw1 = (const float*)d_in[2];
    const float* db1 = (const float*)d_in[3];
    const float* dw2 = (const float*)d_in[4];
    const float* db2 = (const float*)d_in[5];
    const float* dw3 = (const float*)d_in[6];
    const float* db3 = (const float*)d_in[7];
    const float* dw4 = (const float*)d_in[8];
    const float* db4 = (const float*)d_in[9];
    const float* cw1 = (const float*)d_in[10];
    const float* cb1 = (const float*)d_in[11];
    const float* cw2 = (const float*)d_in[12];
    const float* cb2 = (const float*)d_in[13];
    const float* cw3 = (const float*)d_in[14];
    const float* cb3 = (const float*)d_in[15];
    const float* cw4 = (const float*)d_in[16];
    const float* cb4 = (const float*)d_in[17];

    float* outp = (float*)d_out;
    char* ws = (char*)d_ws;

    // ---- transformed-weight region (fp16, frag-native) ----
    // ksteps: d1 10*7*9=630 (G4), d2 5*5*7=175 (G4), d3 5*3*4=60 (G2),
    //         c1 1*7*9=63 (G4), c2=d2, c3=d3. bytes = ksteps*G*1024.
    const size_t O_D1 = 0;                        // 2,580,480
    const size_t O_D2 = O_D1 + 2580480;           //   716,800
    const size_t O_D3 = O_D2 + 716800;            //   122,880
    const size_t O_C1 = O_D3 + 122880;            //   258,048
    const size_t O_C2 = O_C1 + 258048;            //   716,800
    const size_t O_C3 = O_C2 + 716800;            //   122,880
    const size_t O_WEND = O_C3 + 122880;          // 4,517,888

    _Float16* bt_d1 = (_Float16*)(ws + O_D1);
    _Float16* bt_d2 = (_Float16*)(ws + O_D2);
    _Float16* bt_d3 = (_Float16*)(ws + O_D3);
    _Float16* bt_c1 = (_Float16*)(ws + O_C1);
    _Float16* bt_c2 = (_Float16*)(ws + O_C2);
    _Float16* bt_c3 = (_Float16*)(ws + O_C3);

    auto T = [&](const float* w, _Float16* bt, int IC, int OC, int G,
                 int K, int R, int ksteps) {
        int n = ksteps * G * 64;
        wtrans_kernel<<<(n + 255) / 256, 256, 0, stream>>>(w, bt, IC, OC, G, K, R, ksteps);
    };
    T(dw1, bt_d1, 200, 100, 4, 7, 9, 630);
    T(dw2, bt_d2, 100, 100, 4, 5, 7, 175);
    T(dw3, bt_d3, 100,  50, 2, 3, 4,  60);
    T(cw1, bt_c1,  15, 100, 4, 7, 9,  63);
    T(cw2, bt_c2, 100, 100, 4, 5, 7, 175);
    T(cw3, bt_c3, 100,  50, 2, 3, 4,  60);

    // ---- activation sizes (f16 elements per image) ----
    // dFc 10*268*268*20 = 14,364,800 ; bufA 5*262*262*20 = 6,864,400 ;
    // bufB 5*258*258*20 = 6,656,400 ; alias in dFc: bufC 3*256*256*20 =
    // 3,932,160 ; disp 65,536 f32 ; wrp 1,310,720.
    const size_t PER_IMG = (14364800ull + 6864400ull + 6656400ull) * 2; // bytes
    int batch = (ws_size >= O_WEND + 4ull * PER_IMG + 1024) ? 4
              : (ws_size >= O_WEND + 2ull * PER_IMG + 1024) ? 2 : 1;

    for (int g0 = 0; g0 < 4; g0 += batch) {
        const int N = batch;
        char* base = ws + O_WEND;
        _Float16* dFc  = (_Float16*)base;
        _Float16* bufA = (_Float16*)(base + 28729600ull * N);
        _Float16* bufB = (_Float16*)(base + (28729600ull + 13728800ull) * N);
        _Float16* bufC = (_Float16*)base;                          // alias dFc
        float*    disp = (float*)(base + 7864320ull * N);          // alias dFc
        _Float16* wrp  = (_Float16*)(base + (7864320ull + 262144ull) * N);

        const float* dFg = dF + (size_t)g0 * 200 * 268 * 268;
        const float* cFg = cF + (size_t)g0 * 22 * 65536;
        float* outg = outp + (size_t)g0 * 3 * 59536;

        convin_kernel<<<dim3(268, 10, N), 256, 0, stream>>>(dFg, dFc, 200);

        // disparity net
        conv_mfma<7, 2, 2, true><<<9 * 33 * N, 256, 0, stream>>>(
            dFc, bt_d1, db1, bufA, 268, 268, 100, 262, 262, 10, 9, 9 * 33,
            14364800L, 6864400L);
        conv_mfma<5, 2, 2, true><<<9 * 33 * N, 256, 0, stream>>>(
            bufA, bt_d2, db2, bufB, 262, 262, 100, 258, 258, 5, 9, 9 * 33,
            6864400L, 6656400L);
        conv_mfma<3, 4, 1, true><<<8 * 16 * N, 256, 0, stream>>>(
            bufB, bt_d3, db3, bufC, 258, 258, 50, 256, 256, 5, 8, 8 * 16,
            6656400L, 3932160L);
        conv1x1_kernel<1><<<dim3(256, N), 256, 0, stream>>>(
            bufC, dw4, db4, disp, 65536, 50, 3932160L, 65536L);

        // warp
        warp_kernel<<<dim3(256, N), 256, 0, stream>>>(disp, cFg, wrp);

        // color net
        conv_mfma<7, 2, 2, true><<<8 * 32 * N, 256, 0, stream>>>(
            wrp, bt_c1, cb1, bufA, 256, 256, 100, 250, 250, 1, 8, 8 * 32,
            1310720L, 6250000L);
        conv_mfma<5, 2, 2, true><<<8 * 31 * N, 256, 0, stream>>>(
            bufA, bt_c2, cb2, bufB, 250, 250, 100, 246, 246, 5, 8, 8 * 31,
            6250000L, 6051600L);
        conv_mfma<3, 4, 1, true><<<8 * 16 * N, 256, 0, stream>>>(
            bufB, bt_c3, cb3, bufC, 246, 246, 50, 244, 244, 5, 8, 8 * 16,
            6051600L, 3932160L);
        conv1x1_kernel<3><<<dim3(233, N), 256, 0, stream>>>(
            bufC, cw4, cb4, outg, 59536, 50, 3932160L, 178608L);
    }
}